// Round 6
// baseline (529.257 us; speedup 1.0000x reference)
//
#include <hip/hip_runtime.h>
#include <hip/hip_fp16.h>
#include <math.h>

typedef _Float16 f16x8 __attribute__((ext_vector_type(8)));
typedef float f32x4 __attribute__((ext_vector_type(4)));

// ---------------- graph preprocessing ----------------

__global__ void k_init(int* __restrict__ ecnt, int* __restrict__ cursor, int N) {
    int i = blockIdx.x * 256 + threadIdx.x;
    if (i < N) { ecnt[i] = 0; cursor[i] = 0; }
}

__global__ void k_edge_count(const int* __restrict__ dst, int* __restrict__ ecnt, int E) {
    int j = (blockIdx.x * 256 + threadIdx.x) * 2;
    if (j + 1 < E) {
        int2 d = *(const int2*)(dst + j);
        atomicAdd(&ecnt[d.x], 1);
        atomicAdd(&ecnt[d.y], 1);
    } else if (j < E) {
        atomicAdd(&ecnt[dst[j]], 1);
    }
}

__global__ void k_scanA(const int* __restrict__ ecnt, int* __restrict__ bsum, int N) {
    int t = threadIdx.x;
    int base = blockIdx.x * 1024;
    int s = 0;
#pragma unroll
    for (int j = 0; j < 4; ++j) {
        int i = base + j * 256 + t;
        if (i < N) s += ecnt[i];
    }
#pragma unroll
    for (int off = 32; off > 0; off >>= 1) s += __shfl_down(s, off, 64);
    __shared__ int wsum[4];
    if ((t & 63) == 0) wsum[t >> 6] = s;
    __syncthreads();
    if (t == 0) bsum[blockIdx.x] = wsum[0] + wsum[1] + wsum[2] + wsum[3];
}

__global__ void k_scanB(const int* __restrict__ bsum, int* __restrict__ boff, int NB,
                        int* __restrict__ rowstart, int N, int E) {
    __shared__ int sh[256];
    int t = threadIdx.x;
    int v = (t < NB) ? bsum[t] : 0;
    sh[t] = v;
    __syncthreads();
    for (int off = 1; off < 256; off <<= 1) {
        int u = (t >= off) ? sh[t - off] : 0;
        __syncthreads();
        sh[t] += u;
        __syncthreads();
    }
    if (t < NB) boff[t] = sh[t] - v;  // exclusive
    if (t == 0) rowstart[N] = E;
}

__global__ void k_scanC(const int* __restrict__ ecnt, const int* __restrict__ boff,
                        int* __restrict__ rowstart, float* __restrict__ dinv, int N) {
    int t = threadIdx.x;
    int base = blockIdx.x * 1024 + t * 4;
    int e[4];
    int s = 0;
#pragma unroll
    for (int j = 0; j < 4; ++j) {
        int i = base + j;
        e[j] = (i < N) ? ecnt[i] : 0;
        s += e[j];
    }
    __shared__ int sh[256];
    sh[t] = s;
    __syncthreads();
    for (int off = 1; off < 256; off <<= 1) {
        int u = (t >= off) ? sh[t - off] : 0;
        __syncthreads();
        sh[t] += u;
        __syncthreads();
    }
    int off0 = boff[blockIdx.x] + sh[t] - s;
    int run = 0;
#pragma unroll
    for (int j = 0; j < 4; ++j) {
        int i = base + j;
        if (i < N) {
            rowstart[i] = off0 + run;
            dinv[i] = rsqrtf((float)(e[j] + 1));  // +1 self loop
        }
        run += e[j];
    }
}

__global__ void k_scatter(const int* __restrict__ src, const int* __restrict__ dst,
                          const int* __restrict__ rowstart, int* __restrict__ cursor,
                          int* __restrict__ ssrc, int E) {
    int j = (blockIdx.x * 256 + threadIdx.x) * 2;
    if (j + 1 < E) {
        int2 s = *(const int2*)(src + j);
        int2 d = *(const int2*)(dst + j);
        int p0 = rowstart[d.x] + atomicAdd(&cursor[d.x], 1);
        ssrc[p0] = s.x;
        int p1 = rowstart[d.y] + atomicAdd(&cursor[d.y], 1);
        ssrc[p1] = s.y;
    } else if (j < E) {
        int v = dst[j];
        int p = rowstart[v] + atomicAdd(&cursor[v], 1);
        ssrc[p] = src[j];
    }
}

// gstarts + pooled zero-init (grid must cover max(N, G*256) threads)
__global__ void k_gstarts(const int* __restrict__ batch, int* __restrict__ gstart,
                          float* __restrict__ pooled, int N, int G) {
    int i = blockIdx.x * 256 + threadIdx.x;
    if (i < G * 256) pooled[i] = 0.f;
    if (i >= N) return;
    int bi = batch[i];
    int bp = (i == 0) ? -1 : batch[i - 1];
    for (int g = bp + 1; g <= bi; ++g) gstart[g] = i;
    if (i == N - 1) {
        for (int g = bi + 1; g <= G; ++g) gstart[g] = N;
    }
}

// ---------------- f32 -> f16 cast (streaming) ----------------

__global__ __launch_bounds__(256) void k_cast_f2h(const float* __restrict__ in,
                                                  __half* __restrict__ out, int n4) {
    int i = blockIdx.x * 256 + threadIdx.x;
    if (i >= n4) return;
    float4 v = *(const float4*)(in + (size_t)i * 4);
    __half2 a = __floats2half2_rn(v.x, v.y);
    __half2 b = __floats2half2_rn(v.z, v.w);
    union { __half2 h[2]; float2 f; } u;
    u.h[0] = a; u.h[1] = b;
    *(float2*)(out + (size_t)i * 4) = u.f;
}

// ---------------- weight transpose + cast: W[K][256] f32 -> Wt[256][K] f16 ----------------

__global__ __launch_bounds__(256) void k_wt(const float* __restrict__ W,
                                            _Float16* __restrict__ Wt, int K) {
    int idx = blockIdx.x * 256 + threadIdx.x;
    if (idx >= K * 256) return;
    int c = idx / K, k = idx - c * K;
    Wt[idx] = (_Float16)W[k * 256 + c];
}

// ---------------- layer-1 input aggregation ----------------
// xa_h[v] = (half) dinv[v]*(dinv[v]*x[v] + sum dinv[u]*xh[u]); 128 dims
// quarter-wave (16 lanes) per node, f16x8 (16B) per lane

__global__ __launch_bounds__(256) void k_agg_in(
    const float* __restrict__ x, const _Float16* __restrict__ xh,
    const int* __restrict__ rowstart, const int* __restrict__ ssrc,
    const float* __restrict__ dinv, _Float16* __restrict__ xa_h, int N) {
    int qw = threadIdx.x >> 4;
    int l = threadIdx.x & 15;
    int v = blockIdx.x * 16 + qw;
    if (v >= N) return;
    float dv = dinv[v];
    float acc[8];
    {
        float4 s0 = *(const float4*)(x + (size_t)v * 128 + l * 8);
        float4 s1 = *(const float4*)(x + (size_t)v * 128 + l * 8 + 4);
        acc[0] = s0.x * dv; acc[1] = s0.y * dv; acc[2] = s0.z * dv; acc[3] = s0.w * dv;
        acc[4] = s1.x * dv; acc[5] = s1.y * dv; acc[6] = s1.z * dv; acc[7] = s1.w * dv;
    }
    int e = rowstart[v], e1 = rowstart[v + 1];
    for (; e + 4 <= e1; e += 4) {
        int u0 = ssrc[e], u1 = ssrc[e + 1], u2 = ssrc[e + 2], u3 = ssrc[e + 3];
        float d0 = dinv[u0], d1 = dinv[u1], d2 = dinv[u2], d3 = dinv[u3];
        f16x8 m0 = *(const f16x8*)(xh + (size_t)u0 * 128 + l * 8);
        f16x8 m1 = *(const f16x8*)(xh + (size_t)u1 * 128 + l * 8);
        f16x8 m2 = *(const f16x8*)(xh + (size_t)u2 * 128 + l * 8);
        f16x8 m3 = *(const f16x8*)(xh + (size_t)u3 * 128 + l * 8);
#pragma unroll
        for (int j = 0; j < 8; ++j) {
            acc[j] = fmaf((float)m0[j], d0, acc[j]);
            acc[j] = fmaf((float)m1[j], d1, acc[j]);
            acc[j] = fmaf((float)m2[j], d2, acc[j]);
            acc[j] = fmaf((float)m3[j], d3, acc[j]);
        }
    }
    for (; e < e1; ++e) {
        int u = ssrc[e];
        float d = dinv[u];
        f16x8 m = *(const f16x8*)(xh + (size_t)u * 128 + l * 8);
#pragma unroll
        for (int j = 0; j < 8; ++j) acc[j] = fmaf((float)m[j], d, acc[j]);
    }
    f16x8 o;
#pragma unroll
    for (int j = 0; j < 8; ++j) o[j] = (_Float16)(acc[j] * dv);
    *(f16x8*)(xa_h + (size_t)v * 128 + l * 8) = o;
}

// ---------------- layer-2 aggregation + fused graph-mean pooling ----------------
// per node v: o = relu(dinv[v]*(hsh[v] + sum hsh[u]) + b)  [256 dims]
// half-wave (32 lanes, f16x8 per lane) per node; 8 consecutive nodes per half-wave;
// per-graph partial sums kept in registers, flushed by atomicAdd on graph change.

__global__ __launch_bounds__(256) void k_aggpool(
    const _Float16* __restrict__ hsh, const int* __restrict__ rowstart,
    const int* __restrict__ ssrc, const float* __restrict__ dinv,
    const float* __restrict__ bias, const int* __restrict__ batch,
    float* __restrict__ pooled, int N) {
    int hw = threadIdx.x >> 5;
    int l = threadIdx.x & 31;
    int n0 = (blockIdx.x * 8 + hw) * 8;
    if (n0 >= N) return;
    int n1 = n0 + 8 < N ? n0 + 8 : N;

    float b8[8];
#pragma unroll
    for (int j = 0; j < 8; ++j) b8[j] = bias[l * 8 + j];

    float accg[8] = {0.f, 0.f, 0.f, 0.f, 0.f, 0.f, 0.f, 0.f};
    int curg = -1;

    for (int n = n0; n < n1; ++n) {
        float acc[8];
        {
            f16x8 s = *(const f16x8*)(hsh + (size_t)n * 256 + l * 8);  // self loop
#pragma unroll
            for (int j = 0; j < 8; ++j) acc[j] = (float)s[j];
        }
        int e = rowstart[n], e1 = rowstart[n + 1];
        for (; e + 4 <= e1; e += 4) {
            int u0 = ssrc[e], u1 = ssrc[e + 1], u2 = ssrc[e + 2], u3 = ssrc[e + 3];
            f16x8 m0 = *(const f16x8*)(hsh + (size_t)u0 * 256 + l * 8);
            f16x8 m1 = *(const f16x8*)(hsh + (size_t)u1 * 256 + l * 8);
            f16x8 m2 = *(const f16x8*)(hsh + (size_t)u2 * 256 + l * 8);
            f16x8 m3 = *(const f16x8*)(hsh + (size_t)u3 * 256 + l * 8);
#pragma unroll
            for (int j = 0; j < 8; ++j)
                acc[j] += (float)m0[j] + (float)m1[j] + (float)m2[j] + (float)m3[j];
        }
        for (; e < e1; ++e) {
            int u = ssrc[e];
            f16x8 m = *(const f16x8*)(hsh + (size_t)u * 256 + l * 8);
#pragma unroll
            for (int j = 0; j < 8; ++j) acc[j] += (float)m[j];
        }
        float d = dinv[n];
        int g = batch[n];
        if (g != curg) {
            if (curg >= 0) {
#pragma unroll
                for (int j = 0; j < 8; ++j)
                    atomicAdd(&pooled[(size_t)curg * 256 + l * 8 + j], accg[j]);
            }
            curg = g;
#pragma unroll
            for (int j = 0; j < 8; ++j) accg[j] = 0.f;
        }
#pragma unroll
        for (int j = 0; j < 8; ++j)
            accg[j] += fmaxf(fmaf(acc[j], d, b8[j]), 0.f);
    }
    if (curg >= 0) {
#pragma unroll
        for (int j = 0; j < 8; ++j)
            atomicAdd(&pooled[(size_t)curg * 256 + l * 8 + j], accg[j]);
    }
}

// ---------------- MFMA fp16 GEMM ----------------
// C[N x 256] = A[N x K] @ W[K x 256], A fp16, Wt[256][K] fp16 (pre-transposed), f32 accum.
// Block = 4 waves; wave w owns cols [64w, 64w+64) with B held in registers.
// Grid-stride over 64-row chunks; A tile staged to LDS via global_load_lds with
// pre-swizzled source (XOR bits 4-6 with row&7); swizzled ds_read_b128 a-frags.
// EPI 0: Ch = (half)(dinv[r] * acc)      EPI 1: Ch = (half)relu(acc + bias[c])

template<int K, int EPI>
__global__ __launch_bounds__(256, 2) void k_gemm_mfma(
    const _Float16* __restrict__ Ah, const _Float16* __restrict__ Wt,
    const float* __restrict__ dinv, const float* __restrict__ bias,
    _Float16* __restrict__ Ch, int Nrows, int nchunks) {
    constexpr int KS = K / 32;       // k-steps of 32
    constexpr int RB = 2 * K;        // row bytes in A / LDS tile
    constexpr int NLD = 64 * RB / 4096;  // global_load_lds issues per thread
    __shared__ _Float16 As[64 * K];

    int tid = threadIdx.x;
    int l = tid & 63;
    int wv = tid >> 6;

    // ---- B prologue: 4 col-tiles x KS k-steps, registers
    int bc = wv * 64 + (l & 15);
    int bk = (l >> 4) * 8;
    f16x8 breg[4][KS];
#pragma unroll
    for (int ct = 0; ct < 4; ++ct)
#pragma unroll
        for (int ks = 0; ks < KS; ++ks)
            breg[ct][ks] = *(const f16x8*)(Wt + (size_t)(bc + ct * 16) * K + ks * 32 + bk);
    float bb[4];
    if (EPI == 1) {
#pragma unroll
        for (int ct = 0; ct < 4; ++ct) bb[ct] = bias[bc + ct * 16];
    }

    for (int ch = blockIdx.x; ch < nchunks; ch += gridDim.x) {
        int r0 = ch * 64;
        // ---- stage A tile (64 x K fp16), source pre-swizzled, LDS linear
#pragma unroll
        for (int i = 0; i < NLD; ++i) {
            int logical = i * 4096 + tid * 16;
            int row = logical / RB;
            int colb = (logical & (RB - 1)) ^ ((row & 7) << 4);
            int grow = r0 + row;
            grow = grow < Nrows ? grow : Nrows - 1;
            const char* src = (const char*)Ah + (size_t)grow * RB + colb;
            char* dst = (char*)As + i * 4096 + wv * 1024;
            __builtin_amdgcn_global_load_lds(
                (const __attribute__((address_space(1))) void*)src,
                (__attribute__((address_space(3))) void*)dst, 16, 0, 0);
        }
        __syncthreads();   // compiler drains vmcnt before s_barrier

        // ---- compute: 4 row-blocks x KS x 4 col-tiles
#pragma unroll
        for (int rb = 0; rb < 4; ++rb) {
            f32x4 acc[4];
#pragma unroll
            for (int ct = 0; ct < 4; ++ct) acc[ct] = (f32x4){0.f, 0.f, 0.f, 0.f};
            int row = rb * 16 + (l & 15);
#pragma unroll
            for (int ks = 0; ks < KS; ++ks) {
                int lb = (row * RB + ks * 64 + (l >> 4) * 16) ^ ((l & 7) << 4);
                f16x8 a = *(const f16x8*)((const char*)As + lb);
#pragma unroll
                for (int ct = 0; ct < 4; ++ct)
                    acc[ct] = __builtin_amdgcn_mfma_f32_16x16x32_f16(a, breg[ct][ks], acc[ct], 0, 0, 0);
            }
            // ---- epilogue for this row-block
            int rbase = r0 + rb * 16 + (l >> 4) * 4;
#pragma unroll
            for (int j = 0; j < 4; ++j) {
                int r = rbase + j;
                if (r < Nrows) {
                    if (EPI == 0) {
                        float sc = dinv[r];
#pragma unroll
                        for (int ct = 0; ct < 4; ++ct)
                            Ch[(size_t)r * 256 + bc + ct * 16] = (_Float16)(acc[ct][j] * sc);
                    } else {
#pragma unroll
                        for (int ct = 0; ct < 4; ++ct)
                            Ch[(size_t)r * 256 + bc + ct * 16] =
                                (_Float16)fmaxf(acc[ct][j] + bb[ct], 0.f);
                    }
                }
            }
        }
        __syncthreads();   // protect As before next stage
    }
}

// ---------------- head: out[g] = dot(pooled[g]/cnt[g], Wl) + bl ----------------
// one wave per graph

__global__ __launch_bounds__(256) void k_head(
    const float* __restrict__ pooled, const int* __restrict__ gstart,
    const float* __restrict__ Wl, const float* __restrict__ bl,
    float* __restrict__ out, int G) {
    int g = blockIdx.x * 4 + (threadIdx.x >> 6);
    int l = threadIdx.x & 63;
    if (g >= G) return;
    float cnt = fmaxf((float)(gstart[g + 1] - gstart[g]), 1.f);
    float s = 0.f;
#pragma unroll
    for (int j = 0; j < 4; ++j) {
        int c = l * 4 + j;
        s = fmaf(pooled[(size_t)g * 256 + c], Wl[c], s);
    }
#pragma unroll
    for (int off = 32; off > 0; off >>= 1) s += __shfl_down(s, off, 64);
    if (l == 0) out[g] = s / cnt + bl[0];
}

// ---------------- launch ----------------

extern "C" void kernel_launch(void* const* d_in, const int* in_sizes, int n_in,
                              void* d_out, int out_size, void* d_ws, size_t ws_size,
                              hipStream_t stream) {
    const float* x  = (const float*)d_in[0];
    const int* ei   = (const int*)d_in[1];
    const int* batch= (const int*)d_in[2];
    const float* W1 = (const float*)d_in[3];
    const float* b1 = (const float*)d_in[4];
    const float* W2 = (const float*)d_in[5];
    const float* b2 = (const float*)d_in[6];
    const float* Wl = (const float*)d_in[7];
    const float* bl = (const float*)d_in[8];
    float* out = (float*)d_out;

    const int N = in_sizes[2];
    const int E = in_sizes[1] / 2;
    const int G = out_size;

    // Workspace: same footprint family as R4/R5's passing layout.
    char* wsp = (char*)d_ws;
    size_t off = 0;
    auto carve = [&](size_t bytes) -> void* {
        void* p = wsp + off;
        off = (off + bytes + 255) & ~(size_t)255;
        return p;
    };
    float* bufA    = (float*)carve((size_t)N * 256 * 4);
    float* bufB    = (float*)carve((size_t)N * 256 * 4);
    float* dinv    = (float*)carve((size_t)N * 4);
    int* ecnt      = (int*)carve((size_t)N * 4);
    int* rowstart  = (int*)carve((size_t)(N + 1) * 4);
    int* cursor    = (int*)carve((size_t)N * 4);
    int* ssrc      = (int*)carve((size_t)E * 4);
    const int NB = (N + 1023) / 1024;
    int* bsum      = (int*)carve((size_t)NB * 4);
    int* boff      = (int*)carve((size_t)NB * 4);
    int* gstart    = (int*)carve((size_t)(G + 1) * 4);
    _Float16* W1t  = (_Float16*)carve((size_t)256 * 128 * 2);
    _Float16* W2t  = (_Float16*)carve((size_t)256 * 256 * 2);
    float* pooled  = (float*)carve((size_t)G * 256 * 4);
    (void)ws_size;

    // aliases into bufA/bufB (liveness-checked, sequential stream):
    _Float16* xh   = (_Float16*)bufA;                                 // [N*128 f16]
    _Float16* xa_h = (_Float16*)((char*)bufA + (size_t)N * 128 * 2);  // [N*128 f16]
    _Float16* h1h  = (_Float16*)((char*)bufA + (size_t)N * 128 * 4);  // [N*256 f16]
    _Float16* hsh  = (_Float16*)bufB;                                 // [N*256 f16]

    const int* esrc = ei;
    const int* edst = ei + E;

    int nb256 = (N + 255) / 256;
    int nchunks = (N + 63) / 64;
    int gzb = (G * 256 + 255) / 256;          // covers pooled zero-init
    int gsblocks = gzb > nb256 ? gzb : nb256; // also covers batch scan

    hipLaunchKernelGGL(k_init, dim3(nb256), dim3(256), 0, stream, ecnt, cursor, N);
    hipLaunchKernelGGL(k_edge_count, dim3((E / 2 + 255) / 256), dim3(256), 0, stream, edst, ecnt, E);
    hipLaunchKernelGGL(k_scanA, dim3(NB), dim3(256), 0, stream, ecnt, bsum, N);
    hipLaunchKernelGGL(k_scanB, dim3(1), dim3(256), 0, stream, bsum, boff, NB, rowstart, N, E);
    hipLaunchKernelGGL(k_scanC, dim3(NB), dim3(256), 0, stream, ecnt, boff, rowstart, dinv, N);
    hipLaunchKernelGGL(k_scatter, dim3((E / 2 + 255) / 256), dim3(256), 0, stream,
                       esrc, edst, rowstart, cursor, ssrc, E);
    hipLaunchKernelGGL(k_gstarts, dim3(gsblocks), dim3(256), 0, stream, batch, gstart, pooled, N, G);
    hipLaunchKernelGGL(k_cast_f2h, dim3((N * 32 + 255) / 256), dim3(256), 0, stream,
                       x, (__half*)xh, N * 32);
    hipLaunchKernelGGL(k_wt, dim3(128), dim3(256), 0, stream, W1, W1t, 128);
    hipLaunchKernelGGL(k_wt, dim3(256), dim3(256), 0, stream, W2, W2t, 256);

    // layer 1: xa_h = (half) Ahat x ; h1h = (half) relu(xa_h @ W1 + b1)
    hipLaunchKernelGGL(k_agg_in, dim3((N + 15) / 16), dim3(256), 0, stream,
                       x, xh, rowstart, ssrc, dinv, xa_h, N);
    hipLaunchKernelGGL((k_gemm_mfma<128, 1>), dim3(512), dim3(256), 0, stream,
                       xa_h, W1t, (const float*)nullptr, b1, h1h, N, nchunks);
    // layer 2: hsh = (half)(dinv * (h1h @ W2)); aggregate + pooled atomics
    hipLaunchKernelGGL((k_gemm_mfma<256, 0>), dim3(512), dim3(256), 0, stream,
                       h1h, W2t, dinv, (const float*)nullptr, hsh, N, nchunks);
    hipLaunchKernelGGL(k_aggpool, dim3((N + 63) / 64), dim3(256), 0, stream,
                       hsh, rowstart, ssrc, dinv, b2, batch, pooled, N);
    // head
    hipLaunchKernelGGL(k_head, dim3((G + 3) / 4), dim3(256), 0, stream,
                       pooled, gstart, Wl, bl, out, G);
}

// Round 7
// 477.519 us; speedup vs baseline: 1.1083x; 1.1083x over previous
//
#include <hip/hip_runtime.h>
#include <hip/hip_fp16.h>
#include <math.h>

typedef _Float16 f16x8 __attribute__((ext_vector_type(8)));
typedef float f32x4 __attribute__((ext_vector_type(4)));

// ---------------- graph preprocessing ----------------

__global__ void k_init(int* __restrict__ ecnt, int* __restrict__ cursor, int N) {
    int i = blockIdx.x * 256 + threadIdx.x;
    if (i < N) { ecnt[i] = 0; cursor[i] = 0; }
}

__global__ void k_edge_count(const int* __restrict__ dst, int* __restrict__ ecnt, int E) {
    int j = (blockIdx.x * 256 + threadIdx.x) * 2;
    if (j + 1 < E) {
        int2 d = *(const int2*)(dst + j);
        atomicAdd(&ecnt[d.x], 1);
        atomicAdd(&ecnt[d.y], 1);
    } else if (j < E) {
        atomicAdd(&ecnt[dst[j]], 1);
    }
}

__global__ void k_scanA(const int* __restrict__ ecnt, int* __restrict__ bsum, int N) {
    int t = threadIdx.x;
    int base = blockIdx.x * 1024;
    int s = 0;
#pragma unroll
    for (int j = 0; j < 4; ++j) {
        int i = base + j * 256 + t;
        if (i < N) s += ecnt[i];
    }
#pragma unroll
    for (int off = 32; off > 0; off >>= 1) s += __shfl_down(s, off, 64);
    __shared__ int wsum[4];
    if ((t & 63) == 0) wsum[t >> 6] = s;
    __syncthreads();
    if (t == 0) bsum[blockIdx.x] = wsum[0] + wsum[1] + wsum[2] + wsum[3];
}

__global__ void k_scanB(const int* __restrict__ bsum, int* __restrict__ boff, int NB,
                        int* __restrict__ rowstart, int N, int E) {
    __shared__ int sh[256];
    int t = threadIdx.x;
    int v = (t < NB) ? bsum[t] : 0;
    sh[t] = v;
    __syncthreads();
    for (int off = 1; off < 256; off <<= 1) {
        int u = (t >= off) ? sh[t - off] : 0;
        __syncthreads();
        sh[t] += u;
        __syncthreads();
    }
    if (t < NB) boff[t] = sh[t] - v;  // exclusive
    if (t == 0) rowstart[N] = E;
}

__global__ void k_scanC(const int* __restrict__ ecnt, const int* __restrict__ boff,
                        int* __restrict__ rowstart, float* __restrict__ dinv, int N) {
    int t = threadIdx.x;
    int base = blockIdx.x * 1024 + t * 4;
    int e[4];
    int s = 0;
#pragma unroll
    for (int j = 0; j < 4; ++j) {
        int i = base + j;
        e[j] = (i < N) ? ecnt[i] : 0;
        s += e[j];
    }
    __shared__ int sh[256];
    sh[t] = s;
    __syncthreads();
    for (int off = 1; off < 256; off <<= 1) {
        int u = (t >= off) ? sh[t - off] : 0;
        __syncthreads();
        sh[t] += u;
        __syncthreads();
    }
    int off0 = boff[blockIdx.x] + sh[t] - s;
    int run = 0;
#pragma unroll
    for (int j = 0; j < 4; ++j) {
        int i = base + j;
        if (i < N) {
            rowstart[i] = off0 + run;
            dinv[i] = rsqrtf((float)(e[j] + 1));  // +1 self loop
        }
        run += e[j];
    }
}

__global__ void k_scatter(const int* __restrict__ src, const int* __restrict__ dst,
                          const int* __restrict__ rowstart, int* __restrict__ cursor,
                          int* __restrict__ ssrc, int E) {
    int j = (blockIdx.x * 256 + threadIdx.x) * 2;
    if (j + 1 < E) {
        int2 s = *(const int2*)(src + j);
        int2 d = *(const int2*)(dst + j);
        int p0 = rowstart[d.x] + atomicAdd(&cursor[d.x], 1);
        ssrc[p0] = s.x;
        int p1 = rowstart[d.y] + atomicAdd(&cursor[d.y], 1);
        ssrc[p1] = s.y;
    } else if (j < E) {
        int v = dst[j];
        int p = rowstart[v] + atomicAdd(&cursor[v], 1);
        ssrc[p] = src[j];
    }
}

__global__ void k_gstarts(const int* __restrict__ batch, int* __restrict__ gstart, int N, int G) {
    int i = blockIdx.x * 256 + threadIdx.x;
    if (i >= N) return;
    int bi = batch[i];
    int bp = (i == 0) ? -1 : batch[i - 1];
    for (int g = bp + 1; g <= bi; ++g) gstart[g] = i;
    if (i == N - 1) {
        for (int g = bi + 1; g <= G; ++g) gstart[g] = N;
    }
}

// ---------------- f32 -> f16 cast (streaming) ----------------

__global__ __launch_bounds__(256) void k_cast_f2h(const float* __restrict__ in,
                                                  __half* __restrict__ out, int n4) {
    int i = blockIdx.x * 256 + threadIdx.x;
    if (i >= n4) return;
    float4 v = *(const float4*)(in + (size_t)i * 4);
    __half2 a = __floats2half2_rn(v.x, v.y);
    __half2 b = __floats2half2_rn(v.z, v.w);
    union { __half2 h[2]; float2 f; } u;
    u.h[0] = a; u.h[1] = b;
    *(float2*)(out + (size_t)i * 4) = u.f;
}

// ---------------- weight transpose + cast (both layers in one launch) ----------------
// W1[128][256] -> W1t[256][128], W2[256][256] -> W2t[256][256], f32 -> f16

__global__ __launch_bounds__(256) void k_wt_both(
    const float* __restrict__ W1, const float* __restrict__ W2,
    _Float16* __restrict__ W1t, _Float16* __restrict__ W2t) {
    int idx = blockIdx.x * 256 + threadIdx.x;
    if (idx < 128 * 256) {
        int c = idx >> 7, k = idx & 127;
        W1t[idx] = (_Float16)W1[k * 256 + c];
    } else if (idx < 128 * 256 + 256 * 256) {
        int j = idx - 128 * 256;
        int c = j >> 8, k = j & 255;
        W2t[j] = (_Float16)W2[k * 256 + c];
    }
}

// ---------------- layer-1 input aggregation ----------------
// xa_h[v] = (half) dinv[v]*(dinv[v]*xh[v] + sum dinv[u]*xh[u]); 128 dims, all fp16 reads
// quarter-wave (16 lanes) per node, f16x8 (16B) per lane

__global__ __launch_bounds__(256) void k_agg_in(
    const _Float16* __restrict__ xh,
    const int* __restrict__ rowstart, const int* __restrict__ ssrc,
    const float* __restrict__ dinv, _Float16* __restrict__ xa_h, int N) {
    int qw = threadIdx.x >> 4;
    int l = threadIdx.x & 15;
    int v = blockIdx.x * 16 + qw;
    if (v >= N) return;
    float dv = dinv[v];
    float acc[8];
    {
        f16x8 s = *(const f16x8*)(xh + (size_t)v * 128 + l * 8);
#pragma unroll
        for (int j = 0; j < 8; ++j) acc[j] = (float)s[j] * dv;
    }
    int e = rowstart[v], e1 = rowstart[v + 1];
    for (; e + 4 <= e1; e += 4) {
        int u0 = ssrc[e], u1 = ssrc[e + 1], u2 = ssrc[e + 2], u3 = ssrc[e + 3];
        float d0 = dinv[u0], d1 = dinv[u1], d2 = dinv[u2], d3 = dinv[u3];
        f16x8 m0 = *(const f16x8*)(xh + (size_t)u0 * 128 + l * 8);
        f16x8 m1 = *(const f16x8*)(xh + (size_t)u1 * 128 + l * 8);
        f16x8 m2 = *(const f16x8*)(xh + (size_t)u2 * 128 + l * 8);
        f16x8 m3 = *(const f16x8*)(xh + (size_t)u3 * 128 + l * 8);
#pragma unroll
        for (int j = 0; j < 8; ++j) {
            acc[j] = fmaf((float)m0[j], d0, acc[j]);
            acc[j] = fmaf((float)m1[j], d1, acc[j]);
            acc[j] = fmaf((float)m2[j], d2, acc[j]);
            acc[j] = fmaf((float)m3[j], d3, acc[j]);
        }
    }
    for (; e < e1; ++e) {
        int u = ssrc[e];
        float d = dinv[u];
        f16x8 m = *(const f16x8*)(xh + (size_t)u * 128 + l * 8);
#pragma unroll
        for (int j = 0; j < 8; ++j) acc[j] = fmaf((float)m[j], d, acc[j]);
    }
    f16x8 o;
#pragma unroll
    for (int j = 0; j < 8; ++j) o[j] = (_Float16)(acc[j] * dv);
    *(f16x8*)(xa_h + (size_t)v * 128 + l * 8) = o;
}

// ---------------- layer-2 aggregation (R5-proven shape, fp16 in AND out) ----------------
// h2h[v] = (half) relu(dinv[v]*(hsh[v] + sum hsh[u]) + b); 256 dims
// one wave per node, float2 (4 halves, 8B) per lane

__device__ __forceinline__ void acc_h4s(float4& acc, float2 raw) {
    union { float2 f; __half2 h[2]; } u;
    u.f = raw;
    float2 p0 = __half22float2(u.h[0]);
    float2 p1 = __half22float2(u.h[1]);
    acc.x += p0.x; acc.y += p0.y; acc.z += p1.x; acc.w += p1.y;
}

__global__ __launch_bounds__(256) void k_aggregate(
    const __half* __restrict__ hsh, const int* __restrict__ rowstart,
    const int* __restrict__ ssrc, const float* __restrict__ dinv,
    const float* __restrict__ bias, __half* __restrict__ h2h, int N) {
    int w = threadIdx.x >> 6;
    int l = threadIdx.x & 63;
    int v = blockIdx.x * 4 + w;
    if (v >= N) return;
    float4 acc = make_float4(0.f, 0.f, 0.f, 0.f);
    acc_h4s(acc, *(const float2*)(hsh + (size_t)v * 256 + l * 4));  // self loop
    int e = rowstart[v], e1 = rowstart[v + 1];
    for (; e + 4 <= e1; e += 4) {
        int u0 = ssrc[e], u1 = ssrc[e + 1], u2 = ssrc[e + 2], u3 = ssrc[e + 3];
        float2 m0 = *(const float2*)(hsh + (size_t)u0 * 256 + l * 4);
        float2 m1 = *(const float2*)(hsh + (size_t)u1 * 256 + l * 4);
        float2 m2 = *(const float2*)(hsh + (size_t)u2 * 256 + l * 4);
        float2 m3 = *(const float2*)(hsh + (size_t)u3 * 256 + l * 4);
        acc_h4s(acc, m0);
        acc_h4s(acc, m1);
        acc_h4s(acc, m2);
        acc_h4s(acc, m3);
    }
    for (; e < e1; ++e) {
        int u = ssrc[e];
        acc_h4s(acc, *(const float2*)(hsh + (size_t)u * 256 + l * 4));
    }
    float d = dinv[v];
    float4 b = *(const float4*)(bias + l * 4);
    union { __half2 h[2]; float2 f; } uo;
    uo.h[0] = __floats2half2_rn(fmaxf(fmaf(acc.x, d, b.x), 0.f),
                                fmaxf(fmaf(acc.y, d, b.y), 0.f));
    uo.h[1] = __floats2half2_rn(fmaxf(fmaf(acc.z, d, b.z), 0.f),
                                fmaxf(fmaf(acc.w, d, b.w), 0.f));
    *(float2*)(h2h + (size_t)v * 256 + l * 4) = uo.f;
}

// ---------------- MFMA fp16 GEMM ----------------
// C[N x 256] = A[N x K] @ W[K x 256], A fp16, Wt[256][K] fp16 (pre-transposed), f32 accum.
// Block = 4 waves; wave w owns cols [64w, 64w+64) with B held in registers.
// Grid-stride over 64-row chunks; A tile staged to LDS via global_load_lds with
// pre-swizzled source (XOR bits 4-6 with row&7); swizzled ds_read_b128 a-frags.
// EPI 0: Ch = (half)(dinv[r] * acc)      EPI 1: Ch = (half)relu(acc + bias[c])

template<int K, int EPI>
__global__ __launch_bounds__(256, 2) void k_gemm_mfma(
    const _Float16* __restrict__ Ah, const _Float16* __restrict__ Wt,
    const float* __restrict__ dinv, const float* __restrict__ bias,
    _Float16* __restrict__ Ch, int Nrows, int nchunks) {
    constexpr int KS = K / 32;       // k-steps of 32
    constexpr int RB = 2 * K;        // row bytes in A / LDS tile
    constexpr int NLD = 64 * RB / 4096;  // global_load_lds issues per thread
    __shared__ _Float16 As[64 * K];

    int tid = threadIdx.x;
    int l = tid & 63;
    int wv = tid >> 6;

    // ---- B prologue: 4 col-tiles x KS k-steps, registers
    int bc = wv * 64 + (l & 15);
    int bk = (l >> 4) * 8;
    f16x8 breg[4][KS];
#pragma unroll
    for (int ct = 0; ct < 4; ++ct)
#pragma unroll
        for (int ks = 0; ks < KS; ++ks)
            breg[ct][ks] = *(const f16x8*)(Wt + (size_t)(bc + ct * 16) * K + ks * 32 + bk);
    float bb[4];
    if (EPI == 1) {
#pragma unroll
        for (int ct = 0; ct < 4; ++ct) bb[ct] = bias[bc + ct * 16];
    }

    for (int ch = blockIdx.x; ch < nchunks; ch += gridDim.x) {
        int r0 = ch * 64;
        // ---- stage A tile (64 x K fp16), source pre-swizzled, LDS linear
#pragma unroll
        for (int i = 0; i < NLD; ++i) {
            int logical = i * 4096 + tid * 16;
            int row = logical / RB;
            int colb = (logical & (RB - 1)) ^ ((row & 7) << 4);
            int grow = r0 + row;
            grow = grow < Nrows ? grow : Nrows - 1;
            const char* src = (const char*)Ah + (size_t)grow * RB + colb;
            char* dst = (char*)As + i * 4096 + wv * 1024;
            __builtin_amdgcn_global_load_lds(
                (const __attribute__((address_space(1))) void*)src,
                (__attribute__((address_space(3))) void*)dst, 16, 0, 0);
        }
        __syncthreads();   // compiler drains vmcnt before s_barrier

        // ---- compute: 4 row-blocks x KS x 4 col-tiles
#pragma unroll
        for (int rb = 0; rb < 4; ++rb) {
            f32x4 acc[4];
#pragma unroll
            for (int ct = 0; ct < 4; ++ct) acc[ct] = (f32x4){0.f, 0.f, 0.f, 0.f};
            int row = rb * 16 + (l & 15);
#pragma unroll
            for (int ks = 0; ks < KS; ++ks) {
                int lb = (row * RB + ks * 64 + (l >> 4) * 16) ^ ((l & 7) << 4);
                f16x8 a = *(const f16x8*)((const char*)As + lb);
#pragma unroll
                for (int ct = 0; ct < 4; ++ct)
                    acc[ct] = __builtin_amdgcn_mfma_f32_16x16x32_f16(a, breg[ct][ks], acc[ct], 0, 0, 0);
            }
            // ---- epilogue for this row-block
            int rbase = r0 + rb * 16 + (l >> 4) * 4;
#pragma unroll
            for (int j = 0; j < 4; ++j) {
                int r = rbase + j;
                if (r < Nrows) {
                    if (EPI == 0) {
                        float sc = dinv[r];
#pragma unroll
                        for (int ct = 0; ct < 4; ++ct)
                            Ch[(size_t)r * 256 + bc + ct * 16] = (_Float16)(acc[ct][j] * sc);
                    } else {
#pragma unroll
                        for (int ct = 0; ct < 4; ++ct)
                            Ch[(size_t)r * 256 + bc + ct * 16] =
                                (_Float16)fmaxf(acc[ct][j] + bb[ct], 0.f);
                    }
                }
            }
        }
        __syncthreads();   // protect As before next stage
    }
}

// ---------------- fused pool + head: out[g] = dot(mean_rows(h2h[g]), Wl) + bl ----------------
// one block (256 threads) per graph; thread t owns dim t

__global__ __launch_bounds__(256) void k_poolhead(
    const __half* __restrict__ h2h, const int* __restrict__ gstart,
    const float* __restrict__ Wl, const float* __restrict__ bl,
    float* __restrict__ out, int G) {
    int g = blockIdx.x;
    int t = threadIdx.x;
    int i0 = gstart[g], i1 = gstart[g + 1];
    float s = 0.f;
    for (int i = i0; i < i1; ++i) s += __half2float(h2h[(size_t)i * 256 + t]);
    float pooled = s / fmaxf((float)(i1 - i0), 1.f);
    float v = pooled * Wl[t];
#pragma unroll
    for (int off = 32; off > 0; off >>= 1) v += __shfl_down(v, off, 64);
    __shared__ float red[4];
    if ((t & 63) == 0) red[t >> 6] = v;
    __syncthreads();
    if (t == 0) out[g] = red[0] + red[1] + red[2] + red[3] + bl[0];
}

// ---------------- launch ----------------

extern "C" void kernel_launch(void* const* d_in, const int* in_sizes, int n_in,
                              void* d_out, int out_size, void* d_ws, size_t ws_size,
                              hipStream_t stream) {
    const float* x  = (const float*)d_in[0];
    const int* ei   = (const int*)d_in[1];
    const int* batch= (const int*)d_in[2];
    const float* W1 = (const float*)d_in[3];
    const float* b1 = (const float*)d_in[4];
    const float* W2 = (const float*)d_in[5];
    const float* b2 = (const float*)d_in[6];
    const float* Wl = (const float*)d_in[7];
    const float* bl = (const float*)d_in[8];
    float* out = (float*)d_out;

    const int N = in_sizes[2];
    const int E = in_sizes[1] / 2;
    const int G = out_size;

    // Workspace: same proven footprint family (2 big N*256*4 buffers + small arrays).
    char* wsp = (char*)d_ws;
    size_t off = 0;
    auto carve = [&](size_t bytes) -> void* {
        void* p = wsp + off;
        off = (off + bytes + 255) & ~(size_t)255;
        return p;
    };
    float* bufA    = (float*)carve((size_t)N * 256 * 4);
    float* bufB    = (float*)carve((size_t)N * 256 * 4);
    float* dinv    = (float*)carve((size_t)N * 4);
    int* ecnt      = (int*)carve((size_t)N * 4);
    int* rowstart  = (int*)carve((size_t)(N + 1) * 4);
    int* cursor    = (int*)carve((size_t)N * 4);
    int* ssrc      = (int*)carve((size_t)E * 4);
    const int NB = (N + 1023) / 1024;
    int* bsum      = (int*)carve((size_t)NB * 4);
    int* boff      = (int*)carve((size_t)NB * 4);
    int* gstart    = (int*)carve((size_t)(G + 1) * 4);
    _Float16* W1t  = (_Float16*)carve((size_t)256 * 128 * 2);
    _Float16* W2t  = (_Float16*)carve((size_t)256 * 256 * 2);
    (void)ws_size;

    // aliases (liveness-checked, sequential stream):
    // bufA: xh [0,25.6MB) | xa_h [25.6,51.2) | h1h [51.2,102.4)
    // bufB: hsh [0,51.2)  | h2h [51.2,102.4)   (hsh+h2h live together in aggregate)
    _Float16* xh   = (_Float16*)bufA;
    _Float16* xa_h = (_Float16*)((char*)bufA + (size_t)N * 128 * 2);
    _Float16* h1h  = (_Float16*)((char*)bufA + (size_t)N * 128 * 4);
    _Float16* hsh  = (_Float16*)bufB;
    __half*   h2h  = (__half*)((char*)bufB + (size_t)N * 256 * 2);

    const int* esrc = ei;
    const int* edst = ei + E;

    int nb256 = (N + 255) / 256;
    int nchunks = (N + 63) / 64;

    hipLaunchKernelGGL(k_init, dim3(nb256), dim3(256), 0, stream, ecnt, cursor, N);
    hipLaunchKernelGGL(k_edge_count, dim3((E / 2 + 255) / 256), dim3(256), 0, stream, edst, ecnt, E);
    hipLaunchKernelGGL(k_scanA, dim3(NB), dim3(256), 0, stream, ecnt, bsum, N);
    hipLaunchKernelGGL(k_scanB, dim3(1), dim3(256), 0, stream, bsum, boff, NB, rowstart, N, E);
    hipLaunchKernelGGL(k_scanC, dim3(NB), dim3(256), 0, stream, ecnt, boff, rowstart, dinv, N);
    hipLaunchKernelGGL(k_scatter, dim3((E / 2 + 255) / 256), dim3(256), 0, stream,
                       esrc, edst, rowstart, cursor, ssrc, E);
    hipLaunchKernelGGL(k_gstarts, dim3(nb256), dim3(256), 0, stream, batch, gstart, N, G);
    hipLaunchKernelGGL(k_cast_f2h, dim3((N * 32 + 255) / 256), dim3(256), 0, stream,
                       x, (__half*)xh, N * 32);
    hipLaunchKernelGGL(k_wt_both, dim3((128 * 256 + 256 * 256 + 255) / 256), dim3(256), 0, stream,
                       W1, W2, W1t, W2t);

    // layer 1: xa_h = (half) Ahat x ; h1h = (half) relu(xa_h @ W1 + b1)
    hipLaunchKernelGGL(k_agg_in, dim3((N + 15) / 16), dim3(256), 0, stream,
                       xh, rowstart, ssrc, dinv, xa_h, N);
    hipLaunchKernelGGL((k_gemm_mfma<128, 1>), dim3(512), dim3(256), 0, stream,
                       xa_h, W1t, (const float*)nullptr, b1, h1h, N, nchunks);
    // layer 2: hsh = (half)(dinv * (h1h @ W2)); h2h = (half) relu(dinv*(agg hsh) + b2)
    hipLaunchKernelGGL((k_gemm_mfma<256, 0>), dim3(512), dim3(256), 0, stream,
                       h1h, W2t, dinv, (const float*)nullptr, hsh, N, nchunks);
    hipLaunchKernelGGL(k_aggregate, dim3((N + 3) / 4), dim3(256), 0, stream,
                       (const __half*)hsh, rowstart, ssrc, dinv, b2, h2h, N);
    // fused pool + head
    hipLaunchKernelGGL(k_poolhead, dim3(G), dim3(256), 0, stream,
                       h2h, gstart, Wl, bl, out, G);
}

// Round 8
// 441.534 us; speedup vs baseline: 1.1987x; 1.0815x over previous
//
#include <hip/hip_runtime.h>
#include <hip/hip_fp16.h>
#include <math.h>

typedef _Float16 f16x8 __attribute__((ext_vector_type(8)));
typedef float f32x4 __attribute__((ext_vector_type(4)));

// ---------------- graph preprocessing ----------------

__global__ void k_init(int* __restrict__ ecnt, int N) {
    int i = blockIdx.x * 256 + threadIdx.x;
    if (i < N) ecnt[i] = 0;
}

// counting pass; atomicAdd's return value IS the edge's rank within its dst bucket
__global__ void k_edge_count(const int* __restrict__ dst, int* __restrict__ ecnt,
                             int* __restrict__ rank, int E) {
    int j = (blockIdx.x * 256 + threadIdx.x) * 2;
    if (j + 1 < E) {
        int2 d = *(const int2*)(dst + j);
        int r0 = atomicAdd(&ecnt[d.x], 1);
        int r1 = atomicAdd(&ecnt[d.y], 1);
        *(int2*)(rank + j) = make_int2(r0, r1);
    } else if (j < E) {
        rank[j] = atomicAdd(&ecnt[dst[j]], 1);
    }
}

__global__ void k_scanA(const int* __restrict__ ecnt, int* __restrict__ bsum, int N) {
    int t = threadIdx.x;
    int base = blockIdx.x * 1024;
    int s = 0;
#pragma unroll
    for (int j = 0; j < 4; ++j) {
        int i = base + j * 256 + t;
        if (i < N) s += ecnt[i];
    }
#pragma unroll
    for (int off = 32; off > 0; off >>= 1) s += __shfl_down(s, off, 64);
    __shared__ int wsum[4];
    if ((t & 63) == 0) wsum[t >> 6] = s;
    __syncthreads();
    if (t == 0) bsum[blockIdx.x] = wsum[0] + wsum[1] + wsum[2] + wsum[3];
}

__global__ void k_scanB(const int* __restrict__ bsum, int* __restrict__ boff, int NB,
                        int* __restrict__ rowstart, int N, int E) {
    __shared__ int sh[256];
    int t = threadIdx.x;
    int v = (t < NB) ? bsum[t] : 0;
    sh[t] = v;
    __syncthreads();
    for (int off = 1; off < 256; off <<= 1) {
        int u = (t >= off) ? sh[t - off] : 0;
        __syncthreads();
        sh[t] += u;
        __syncthreads();
    }
    if (t < NB) boff[t] = sh[t] - v;  // exclusive
    if (t == 0) rowstart[N] = E;
}

__global__ void k_scanC(const int* __restrict__ ecnt, const int* __restrict__ boff,
                        int* __restrict__ rowstart, float* __restrict__ dinv, int N) {
    int t = threadIdx.x;
    int base = blockIdx.x * 1024 + t * 4;
    int e[4];
    int s = 0;
#pragma unroll
    for (int j = 0; j < 4; ++j) {
        int i = base + j;
        e[j] = (i < N) ? ecnt[i] : 0;
        s += e[j];
    }
    __shared__ int sh[256];
    sh[t] = s;
    __syncthreads();
    for (int off = 1; off < 256; off <<= 1) {
        int u = (t >= off) ? sh[t - off] : 0;
        __syncthreads();
        sh[t] += u;
        __syncthreads();
    }
    int off0 = boff[blockIdx.x] + sh[t] - s;
    int run = 0;
#pragma unroll
    for (int j = 0; j < 4; ++j) {
        int i = base + j;
        if (i < N) {
            rowstart[i] = off0 + run;
            dinv[i] = rsqrtf((float)(e[j] + 1));  // +1 self loop
        }
        run += e[j];
    }
}

// atomic-free scatter: slot = rowstart[dst] + rank (4 edges/thread, full MLP)
__global__ void k_scatter(const int* __restrict__ src, const int* __restrict__ dst,
                          const int* __restrict__ rowstart, const int* __restrict__ rank,
                          int* __restrict__ ssrc, int E) {
    int j = (blockIdx.x * 256 + threadIdx.x) * 4;
    if (j + 3 < E) {
        int4 s = *(const int4*)(src + j);
        int4 d = *(const int4*)(dst + j);
        int4 r = *(const int4*)(rank + j);
        ssrc[rowstart[d.x] + r.x] = s.x;
        ssrc[rowstart[d.y] + r.y] = s.y;
        ssrc[rowstart[d.z] + r.z] = s.z;
        ssrc[rowstart[d.w] + r.w] = s.w;
    } else {
        for (; j < E; ++j) ssrc[rowstart[dst[j]] + rank[j]] = src[j];
    }
}

__global__ void k_gstarts(const int* __restrict__ batch, int* __restrict__ gstart, int N, int G) {
    int i = blockIdx.x * 256 + threadIdx.x;
    if (i >= N) return;
    int bi = batch[i];
    int bp = (i == 0) ? -1 : batch[i - 1];
    for (int g = bp + 1; g <= bi; ++g) gstart[g] = i;
    if (i == N - 1) {
        for (int g = bi + 1; g <= G; ++g) gstart[g] = N;
    }
}

// ---------------- f32 -> f16 cast (streaming) ----------------

__global__ __launch_bounds__(256) void k_cast_f2h(const float* __restrict__ in,
                                                  __half* __restrict__ out, int n4) {
    int i = blockIdx.x * 256 + threadIdx.x;
    if (i >= n4) return;
    float4 v = *(const float4*)(in + (size_t)i * 4);
    __half2 a = __floats2half2_rn(v.x, v.y);
    __half2 b = __floats2half2_rn(v.z, v.w);
    union { __half2 h[2]; float2 f; } u;
    u.h[0] = a; u.h[1] = b;
    *(float2*)(out + (size_t)i * 4) = u.f;
}

// ---------------- weight transpose + cast (both layers in one launch) ----------------

__global__ __launch_bounds__(256) void k_wt_both(
    const float* __restrict__ W1, const float* __restrict__ W2,
    _Float16* __restrict__ W1t, _Float16* __restrict__ W2t) {
    int idx = blockIdx.x * 256 + threadIdx.x;
    if (idx < 128 * 256) {
        int c = idx >> 7, k = idx & 127;
        W1t[idx] = (_Float16)W1[k * 256 + c];
    } else if (idx < 128 * 256 + 256 * 256) {
        int j = idx - 128 * 256;
        int c = j >> 8, k = j & 255;
        W2t[j] = (_Float16)W2[k * 256 + c];
    }
}

// ---------------- layer-1 input aggregation ----------------
// xa_h[v] = (half) dinv[v]*(dinv[v]*xh[v] + sum dinv[u]*xh[u]); 128 dims, fp16 reads
// quarter-wave (16 lanes) per node, f16x8 (16B) per lane

__global__ __launch_bounds__(256) void k_agg_in(
    const _Float16* __restrict__ xh,
    const int* __restrict__ rowstart, const int* __restrict__ ssrc,
    const float* __restrict__ dinv, _Float16* __restrict__ xa_h, int N) {
    int qw = threadIdx.x >> 4;
    int l = threadIdx.x & 15;
    int v = blockIdx.x * 16 + qw;
    if (v >= N) return;
    float dv = dinv[v];
    float acc[8];
    {
        f16x8 s = *(const f16x8*)(xh + (size_t)v * 128 + l * 8);
#pragma unroll
        for (int j = 0; j < 8; ++j) acc[j] = (float)s[j] * dv;
    }
    int e = rowstart[v], e1 = rowstart[v + 1];
    for (; e + 4 <= e1; e += 4) {
        int u0 = ssrc[e], u1 = ssrc[e + 1], u2 = ssrc[e + 2], u3 = ssrc[e + 3];
        float d0 = dinv[u0], d1 = dinv[u1], d2 = dinv[u2], d3 = dinv[u3];
        f16x8 m0 = *(const f16x8*)(xh + (size_t)u0 * 128 + l * 8);
        f16x8 m1 = *(const f16x8*)(xh + (size_t)u1 * 128 + l * 8);
        f16x8 m2 = *(const f16x8*)(xh + (size_t)u2 * 128 + l * 8);
        f16x8 m3 = *(const f16x8*)(xh + (size_t)u3 * 128 + l * 8);
#pragma unroll
        for (int j = 0; j < 8; ++j) {
            acc[j] = fmaf((float)m0[j], d0, acc[j]);
            acc[j] = fmaf((float)m1[j], d1, acc[j]);
            acc[j] = fmaf((float)m2[j], d2, acc[j]);
            acc[j] = fmaf((float)m3[j], d3, acc[j]);
        }
    }
    for (; e < e1; ++e) {
        int u = ssrc[e];
        float d = dinv[u];
        f16x8 m = *(const f16x8*)(xh + (size_t)u * 128 + l * 8);
#pragma unroll
        for (int j = 0; j < 8; ++j) acc[j] = fmaf((float)m[j], d, acc[j]);
    }
    f16x8 o;
#pragma unroll
    for (int j = 0; j < 8; ++j) o[j] = (_Float16)(acc[j] * dv);
    *(f16x8*)(xa_h + (size_t)v * 128 + l * 8) = o;
}

// ---------------- layer-2 aggregation (proven shape, fp16 in AND out) ----------------
// h2h[v] = (half) relu(dinv[v]*(hsh[v] + sum hsh[u]) + b); 256 dims
// one wave per node, float2 (4 halves, 8B) per lane

__device__ __forceinline__ void acc_h4s(float4& acc, float2 raw) {
    union { float2 f; __half2 h[2]; } u;
    u.f = raw;
    float2 p0 = __half22float2(u.h[0]);
    float2 p1 = __half22float2(u.h[1]);
    acc.x += p0.x; acc.y += p0.y; acc.z += p1.x; acc.w += p1.y;
}

__global__ __launch_bounds__(256) void k_aggregate(
    const __half* __restrict__ hsh, const int* __restrict__ rowstart,
    const int* __restrict__ ssrc, const float* __restrict__ dinv,
    const float* __restrict__ bias, __half* __restrict__ h2h, int N) {
    int w = threadIdx.x >> 6;
    int l = threadIdx.x & 63;
    int v = blockIdx.x * 4 + w;
    if (v >= N) return;
    float4 acc = make_float4(0.f, 0.f, 0.f, 0.f);
    acc_h4s(acc, *(const float2*)(hsh + (size_t)v * 256 + l * 4));  // self loop
    int e = rowstart[v], e1 = rowstart[v + 1];
    for (; e + 4 <= e1; e += 4) {
        int u0 = ssrc[e], u1 = ssrc[e + 1], u2 = ssrc[e + 2], u3 = ssrc[e + 3];
        float2 m0 = *(const float2*)(hsh + (size_t)u0 * 256 + l * 4);
        float2 m1 = *(const float2*)(hsh + (size_t)u1 * 256 + l * 4);
        float2 m2 = *(const float2*)(hsh + (size_t)u2 * 256 + l * 4);
        float2 m3 = *(const float2*)(hsh + (size_t)u3 * 256 + l * 4);
        acc_h4s(acc, m0);
        acc_h4s(acc, m1);
        acc_h4s(acc, m2);
        acc_h4s(acc, m3);
    }
    for (; e < e1; ++e) {
        int u = ssrc[e];
        acc_h4s(acc, *(const float2*)(hsh + (size_t)u * 256 + l * 4));
    }
    float d = dinv[v];
    float4 b = *(const float4*)(bias + l * 4);
    union { __half2 h[2]; float2 f; } uo;
    uo.h[0] = __floats2half2_rn(fmaxf(fmaf(acc.x, d, b.x), 0.f),
                                fmaxf(fmaf(acc.y, d, b.y), 0.f));
    uo.h[1] = __floats2half2_rn(fmaxf(fmaf(acc.z, d, b.z), 0.f),
                                fmaxf(fmaf(acc.w, d, b.w), 0.f));
    *(float2*)(h2h + (size_t)v * 256 + l * 4) = uo.f;
}

// ---------------- MFMA fp16 GEMM ----------------
// C[N x 256] = A[N x K] @ W[K x 256], A fp16, Wt[256][K] fp16 (pre-transposed), f32 accum.
// Block = 4 waves; wave w owns cols [64w, 64w+64) with B held in registers.
// Grid-stride over 64-row chunks; A tile staged to LDS via global_load_lds with
// pre-swizzled source (XOR bits 4-6 with row&7); swizzled ds_read_b128 a-frags.
// EPI 0: Ch = (half)(dinv[r] * acc)      EPI 1: Ch = (half)relu(acc + bias[c])

template<int K, int EPI>
__global__ __launch_bounds__(256, 2) void k_gemm_mfma(
    const _Float16* __restrict__ Ah, const _Float16* __restrict__ Wt,
    const float* __restrict__ dinv, const float* __restrict__ bias,
    _Float16* __restrict__ Ch, int Nrows, int nchunks) {
    constexpr int KS = K / 32;       // k-steps of 32
    constexpr int RB = 2 * K;        // row bytes in A / LDS tile
    constexpr int NLD = 64 * RB / 4096;  // global_load_lds issues per thread
    __shared__ _Float16 As[64 * K];

    int tid = threadIdx.x;
    int l = tid & 63;
    int wv = tid >> 6;

    // ---- B prologue: 4 col-tiles x KS k-steps, registers
    int bc = wv * 64 + (l & 15);
    int bk = (l >> 4) * 8;
    f16x8 breg[4][KS];
#pragma unroll
    for (int ct = 0; ct < 4; ++ct)
#pragma unroll
        for (int ks = 0; ks < KS; ++ks)
            breg[ct][ks] = *(const f16x8*)(Wt + (size_t)(bc + ct * 16) * K + ks * 32 + bk);
    float bb[4];
    if (EPI == 1) {
#pragma unroll
        for (int ct = 0; ct < 4; ++ct) bb[ct] = bias[bc + ct * 16];
    }

    for (int ch = blockIdx.x; ch < nchunks; ch += gridDim.x) {
        int r0 = ch * 64;
        // ---- stage A tile (64 x K fp16), source pre-swizzled, LDS linear
#pragma unroll
        for (int i = 0; i < NLD; ++i) {
            int logical = i * 4096 + tid * 16;
            int row = logical / RB;
            int colb = (logical & (RB - 1)) ^ ((row & 7) << 4);
            int grow = r0 + row;
            grow = grow < Nrows ? grow : Nrows - 1;
            const char* src = (const char*)Ah + (size_t)grow * RB + colb;
            char* dst = (char*)As + i * 4096 + wv * 1024;
            __builtin_amdgcn_global_load_lds(
                (const __attribute__((address_space(1))) void*)src,
                (__attribute__((address_space(3))) void*)dst, 16, 0, 0);
        }
        __syncthreads();   // compiler drains vmcnt before s_barrier

        // ---- compute: 4 row-blocks x KS x 4 col-tiles
#pragma unroll
        for (int rb = 0; rb < 4; ++rb) {
            f32x4 acc[4];
#pragma unroll
            for (int ct = 0; ct < 4; ++ct) acc[ct] = (f32x4){0.f, 0.f, 0.f, 0.f};
            int row = rb * 16 + (l & 15);
#pragma unroll
            for (int ks = 0; ks < KS; ++ks) {
                int lb = (row * RB + ks * 64 + (l >> 4) * 16) ^ ((l & 7) << 4);
                f16x8 a = *(const f16x8*)((const char*)As + lb);
#pragma unroll
                for (int ct = 0; ct < 4; ++ct)
                    acc[ct] = __builtin_amdgcn_mfma_f32_16x16x32_f16(a, breg[ct][ks], acc[ct], 0, 0, 0);
            }
            // ---- epilogue for this row-block
            int rbase = r0 + rb * 16 + (l >> 4) * 4;
#pragma unroll
            for (int j = 0; j < 4; ++j) {
                int r = rbase + j;
                if (r < Nrows) {
                    if (EPI == 0) {
                        float sc = dinv[r];
#pragma unroll
                        for (int ct = 0; ct < 4; ++ct)
                            Ch[(size_t)r * 256 + bc + ct * 16] = (_Float16)(acc[ct][j] * sc);
                    } else {
#pragma unroll
                        for (int ct = 0; ct < 4; ++ct)
                            Ch[(size_t)r * 256 + bc + ct * 16] =
                                (_Float16)fmaxf(acc[ct][j] + bb[ct], 0.f);
                    }
                }
            }
        }
        __syncthreads();   // protect As before next stage
    }
}

// ---------------- fused pool + head ----------------
// one block (256 threads) per graph; thread t owns dim t

__global__ __launch_bounds__(256) void k_poolhead(
    const __half* __restrict__ h2h, const int* __restrict__ gstart,
    const float* __restrict__ Wl, const float* __restrict__ bl,
    float* __restrict__ out, int G) {
    int g = blockIdx.x;
    int t = threadIdx.x;
    int i0 = gstart[g], i1 = gstart[g + 1];
    float s = 0.f;
    for (int i = i0; i < i1; ++i) s += __half2float(h2h[(size_t)i * 256 + t]);
    float pooled = s / fmaxf((float)(i1 - i0), 1.f);
    float v = pooled * Wl[t];
#pragma unroll
    for (int off = 32; off > 0; off >>= 1) v += __shfl_down(v, off, 64);
    __shared__ float red[4];
    if ((t & 63) == 0) red[t >> 6] = v;
    __syncthreads();
    if (t == 0) out[g] = red[0] + red[1] + red[2] + red[3] + bl[0];
}

// ---------------- launch ----------------

extern "C" void kernel_launch(void* const* d_in, const int* in_sizes, int n_in,
                              void* d_out, int out_size, void* d_ws, size_t ws_size,
                              hipStream_t stream) {
    const float* x  = (const float*)d_in[0];
    const int* ei   = (const int*)d_in[1];
    const int* batch= (const int*)d_in[2];
    const float* W1 = (const float*)d_in[3];
    const float* b1 = (const float*)d_in[4];
    const float* W2 = (const float*)d_in[5];
    const float* b2 = (const float*)d_in[6];
    const float* Wl = (const float*)d_in[7];
    const float* bl = (const float*)d_in[8];
    float* out = (float*)d_out;

    const int N = in_sizes[2];
    const int E = in_sizes[1] / 2;
    const int G = out_size;

    // Workspace: same proven footprint family (2 big N*256*4 buffers + small arrays).
    // 'rank' reuses the old cursor slot (E*4 <= prior cursor N*4 + slack? no —
    // rank is E ints; carve it explicitly, cursor is gone).
    char* wsp = (char*)d_ws;
    size_t off = 0;
    auto carve = [&](size_t bytes) -> void* {
        void* p = wsp + off;
        off = (off + bytes + 255) & ~(size_t)255;
        return p;
    };
    float* bufA    = (float*)carve((size_t)N * 256 * 4);
    float* bufB    = (float*)carve((size_t)N * 256 * 4);
    float* dinv    = (float*)carve((size_t)N * 4);
    int* ecnt      = (int*)carve((size_t)N * 4);
    int* rowstart  = (int*)carve((size_t)(N + 1) * 4);
    int* rank      = (int*)carve((size_t)E * 4);
    int* ssrc      = (int*)carve((size_t)E * 4);
    const int NB = (N + 1023) / 1024;
    int* bsum      = (int*)carve((size_t)NB * 4);
    int* boff      = (int*)carve((size_t)NB * 4);
    int* gstart    = (int*)carve((size_t)(G + 1) * 4);
    _Float16* W1t  = (_Float16*)carve((size_t)256 * 128 * 2);
    _Float16* W2t  = (_Float16*)carve((size_t)256 * 256 * 2);
    (void)ws_size;

    // aliases (liveness-checked, sequential stream):
    // bufA: xh [0,25.6MB) | xa_h [25.6,51.2) | h1h [51.2,102.4)
    // bufB: hsh [0,51.2)  | h2h [51.2,102.4)
    _Float16* xh   = (_Float16*)bufA;
    _Float16* xa_h = (_Float16*)((char*)bufA + (size_t)N * 128 * 2);
    _Float16* h1h  = (_Float16*)((char*)bufA + (size_t)N * 128 * 4);
    _Float16* hsh  = (_Float16*)bufB;
    __half*   h2h  = (__half*)((char*)bufB + (size_t)N * 256 * 2);

    const int* esrc = ei;
    const int* edst = ei + E;

    int nb256 = (N + 255) / 256;
    int nchunks = (N + 63) / 64;

    hipLaunchKernelGGL(k_init, dim3(nb256), dim3(256), 0, stream, ecnt, N);
    hipLaunchKernelGGL(k_edge_count, dim3((E / 2 + 255) / 256), dim3(256), 0, stream,
                       edst, ecnt, rank, E);
    hipLaunchKernelGGL(k_scanA, dim3(NB), dim3(256), 0, stream, ecnt, bsum, N);
    hipLaunchKernelGGL(k_scanB, dim3(1), dim3(256), 0, stream, bsum, boff, NB, rowstart, N, E);
    hipLaunchKernelGGL(k_scanC, dim3(NB), dim3(256), 0, stream, ecnt, boff, rowstart, dinv, N);
    hipLaunchKernelGGL(k_scatter, dim3((E / 4 + 255) / 256), dim3(256), 0, stream,
                       esrc, edst, rowstart, rank, ssrc, E);
    hipLaunchKernelGGL(k_gstarts, dim3(nb256), dim3(256), 0, stream, batch, gstart, N, G);
    hipLaunchKernelGGL(k_cast_f2h, dim3((N * 32 + 255) / 256), dim3(256), 0, stream,
                       x, (__half*)xh, N * 32);
    hipLaunchKernelGGL(k_wt_both, dim3((128 * 256 + 256 * 256 + 255) / 256), dim3(256), 0, stream,
                       W1, W2, W1t, W2t);

    // layer 1: xa_h = (half) Ahat x ; h1h = (half) relu(xa_h @ W1 + b1)
    hipLaunchKernelGGL(k_agg_in, dim3((N + 15) / 16), dim3(256), 0, stream,
                       xh, rowstart, ssrc, dinv, xa_h, N);
    hipLaunchKernelGGL((k_gemm_mfma<128, 1>), dim3(512), dim3(256), 0, stream,
                       xa_h, W1t, (const float*)nullptr, b1, h1h, N, nchunks);
    // layer 2: hsh = (half)(dinv * (h1h @ W2)); h2h = (half) relu(dinv*(agg hsh) + b2)
    hipLaunchKernelGGL((k_gemm_mfma<256, 0>), dim3(512), dim3(256), 0, stream,
                       h1h, W2t, dinv, (const float*)nullptr, hsh, N, nchunks);
    hipLaunchKernelGGL(k_aggregate, dim3((N + 3) / 4), dim3(256), 0, stream,
                       (const __half*)hsh, rowstart, ssrc, dinv, b2, h2h, N);
    // fused pool + head
    hipLaunchKernelGGL(k_poolhead, dim3(G), dim3(256), 0, stream,
                       h2h, gstart, Wl, bl, out, G);
}